// Round 4
// baseline (270.840 us; speedup 1.0000x reference)
//
#include <hip/hip_runtime.h>

// (32, 3, 384, 640) fp32 in, (32, 1, 384, 640) fp32 out.
// One thread = 4 horizontally-adjacent output pixels of one row.
// High-TLP design: 7680 blocks / 30720 waves; small register state.
#define BATCH 32
#define CHAN  3
#define HH    384
#define WW    640

__global__ __launch_bounds__(256, 4)
void ssim_l1_kernel(const float* __restrict__ src,
                    const float* __restrict__ tgt,
                    float* __restrict__ out) {
    const int w0 = (blockIdx.x * 32 + threadIdx.x) * 4;
    const int h  = blockIdx.y * 8 + threadIdx.y;
    const int b  = blockIdx.z;

    // reflect-pad(1) edge indices
    const int wm1 = (w0 == 0) ? 1 : w0 - 1;
    const int wp4 = (w0 + 4 >= WW) ? WW - 2 : w0 + 4;
    const int hu  = (h == 0) ? 1 : h - 1;
    const int hd  = (h == HH - 1) ? HH - 2 : h + 1;
    const int rows[3] = { hu, h, hd };

    const float inv9  = 1.0f / 9.0f;
    const float C1v   = 6.5025f;     // (0.01*255)^2
    const float C2v   = 58.5225f;    // (0.03*255)^2
    const float wssim = 0.5f * 0.85f / 3.0f;
    const float wl1   = 0.15f / 3.0f;

    float acc[4] = { 0.f, 0.f, 0.f, 0.f };

#pragma unroll
    for (int c = 0; c < CHAN; c++) {
        const float* __restrict__ xc = src + ((size_t)b * CHAN + c) * (HH * WW);
        const float* __restrict__ yc = tgt + ((size_t)b * CHAN + c) * (HH * WW);

        // per-column vertical accumulators over the 3 rows
        float vx[6], vy[6], vss[6], vxy[6];
#pragma unroll
        for (int i = 0; i < 6; i++) { vx[i] = 0.f; vy[i] = 0.f; vss[i] = 0.f; vxy[i] = 0.f; }
        float dab[4];

#pragma unroll
        for (int r = 0; r < 3; r++) {
            const float* __restrict__ xr = xc + rows[r] * WW;
            const float* __restrict__ yr = yc + rows[r] * WW;
            float4 xv = *(const float4*)(xr + w0);
            float4 yv = *(const float4*)(yr + w0);
            float x[6], y[6];
            x[0] = xr[wm1]; x[1] = xv.x; x[2] = xv.y; x[3] = xv.z; x[4] = xv.w; x[5] = xr[wp4];
            y[0] = yr[wm1]; y[1] = yv.x; y[2] = yv.y; y[3] = yv.z; y[4] = yv.w; y[5] = yr[wp4];
#pragma unroll
            for (int i = 0; i < 6; i++) {
                vx[i]  += x[i];
                vy[i]  += y[i];
                vss[i]  = fmaf(x[i], x[i], fmaf(y[i], y[i], vss[i]));
                vxy[i]  = fmaf(x[i], y[i], vxy[i]);
            }
            if (r == 1) {
#pragma unroll
                for (int k = 0; k < 4; k++) dab[k] = fabsf(x[k + 1] - y[k + 1]);
            }
        }

#pragma unroll
        for (int k = 0; k < 4; k++) {
            float Sx  = vx [k] + vx [k + 1] + vx [k + 2];
            float Sy  = vy [k] + vy [k + 1] + vy [k + 2];
            float Sss = vss[k] + vss[k + 1] + vss[k + 2];
            float Sxy = vxy[k] + vxy[k + 1] + vxy[k + 2];

            float mux = Sx * inv9;
            float muy = Sy * inv9;
            float mm  = mux * muy;
            // sigx + sigy = Sss/9 - mux - muy   (faithful: -mu, not -mu^2)
            float sigsum = fmaf(Sss, inv9, -(mux + muy));
            float sigxy  = fmaf(Sxy, inv9, -mm);

            float num = fmaf(2.0f, mm, C1v) * fmaf(2.0f, sigxy, C2v);
            float den = fmaf(muy, muy, fmaf(mux, mux, C1v)) * (sigsum + C2v);
            float q   = num * __builtin_amdgcn_rcpf(den);
            float ns  = fmaf(q, -0.5f, 0.5f);
            ns = fminf(fmaxf(ns, 0.0f), 1.0f);

            acc[k] = fmaf(wssim, ns, fmaf(wl1, dab[k], acc[k]));
        }
    }

    *(float4*)(out + ((size_t)b * HH + h) * WW + w0) =
        make_float4(acc[0], acc[1], acc[2], acc[3]);
}

extern "C" void kernel_launch(void* const* d_in, const int* in_sizes, int n_in,
                              void* d_out, int out_size, void* d_ws, size_t ws_size,
                              hipStream_t stream) {
    const float* src = (const float*)d_in[0];   // 'output'
    const float* tgt = (const float*)d_in[1];   // 'target'
    float* out = (float*)d_out;

    dim3 grid(WW / (32 * 4), HH / 8, BATCH);    // (5, 48, 32) = 7680 blocks
    dim3 block(32, 8);
    ssim_l1_kernel<<<grid, block, 0, stream>>>(src, tgt, out);
}

// Round 5
// 231.637 us; speedup vs baseline: 1.1692x; 1.1692x over previous
//
#include <hip/hip_runtime.h>

// (32, 3, 384, 640) fp32 in, (32, 1, 384, 640) fp32 out.
// LDS-staged 3x3 stencil: block = 256 threads, 128x16 output tile.
// Per channel: bulk coalesced global->LDS stage (both tensors), barrier,
// compute from LDS. Converts exposed per-wave global latency into one
// amortized bulk wait + cheap pipelined LDS reads.
#define BATCH 32
#define CHAN  3
#define HH    384
#define WW    640
#define HW    (HH * WW)

#define OTW 128            // output tile width
#define OTH 16             // output tile height
#define LW  136            // LDS row width  (cols colbase .. colbase+135)
#define LH  18             // LDS rows       (rows h0-1 .. h0+16)
#define LPLANE (LH * LW)   // 2448 floats per tensor

__device__ __forceinline__ int reflectW(int v) {
    if (v < 0) v = -v;
    if (v >= WW) v = 2 * WW - 2 - v;
    return v;
}
__device__ __forceinline__ int reflectH(int v) {
    if (v < 0) v = -v;
    if (v >= HH) v = 2 * HH - 2 - v;
    return v;
}

__global__ __launch_bounds__(256, 6)
void ssim_l1_kernel(const float* __restrict__ src,
                    const float* __restrict__ tgt,
                    float* __restrict__ out) {
    __shared__ float lds[2 * LPLANE];   // 19584 B -> 8 blocks/CU by LDS

    const int tx  = threadIdx.x;        // 0..31
    const int ty  = threadIdx.y;        // 0..7
    const int tid = ty * 32 + tx;
    const int bx = blockIdx.x, by = blockIdx.y, b = blockIdx.z;

    const int colbase = bx * OTW - 4;   // 16B-aligned global col of LDS col 0
    const int h0 = by * OTH;

    const float inv9  = 1.0f / 9.0f;
    const float C1v   = 6.5025f;        // (0.01*255)^2
    const float C2v   = 58.5225f;       // (0.03*255)^2
    const float wssim = 0.5f * 0.85f / 3.0f;
    const float wl1   = 0.15f / 3.0f;

    float acc[2][4] = {{0.f, 0.f, 0.f, 0.f}, {0.f, 0.f, 0.f, 0.f}};

    const int jc = 4 * tx + 4;          // LDS col of this thread's first out px

#pragma unroll 1
    for (int c = 0; c < CHAN; c++) {
        const float* __restrict__ xp = src + ((size_t)b * CHAN + c) * HW;
        const float* __restrict__ yp = tgt + ((size_t)b * CHAN + c) * HW;

        // ---- stage: 2 tensors x 18 rows x 34 float4-groups = 1224 groups ----
        for (int g = tid; g < 2 * LH * 34; g += 256) {
            const int t  = (g >= LH * 34);
            const int gg = t ? g - LH * 34 : g;
            const int r  = gg / 34;
            const int q  = gg - r * 34;
            const float* __restrict__ pl  = t ? yp : xp;
            const float* __restrict__ row = pl + (size_t)reflectH(h0 - 1 + r) * WW;
            const int gc = colbase + q * 4;
            float4 v;
            if (gc >= 0 && gc + 3 < WW) {
                v = *(const float4*)(row + gc);          // aligned, coalesced
            } else {                                      // edge blocks only
                v.x = row[reflectW(gc)];
                v.y = row[reflectW(gc + 1)];
                v.z = row[reflectW(gc + 2)];
                v.w = row[reflectW(gc + 3)];
            }
            *(float4*)&lds[t * LPLANE + r * LW + q * 4] = v;
        }
        __syncthreads();

        // ---- compute: 2 output rows x 4 px per thread ----
#pragma unroll
        for (int rr = 0; rr < 2; rr++) {
            const int lr0 = 2 * ty + rr;                 // top of 3-row window
            float vx[6], vy[6], vss[6], vxy[6];
#pragma unroll
            for (int i = 0; i < 6; i++) { vx[i] = 0.f; vy[i] = 0.f; vss[i] = 0.f; vxy[i] = 0.f; }
            float dab[4];

#pragma unroll
            for (int r3 = 0; r3 < 3; r3++) {
                const float* __restrict__ lx = &lds[(lr0 + r3) * LW];
                const float* __restrict__ ly = &lds[LPLANE + (lr0 + r3) * LW];
                float4 xm = *(const float4*)(lx + jc);   // 16B-aligned ds_read_b128
                float4 ym = *(const float4*)(ly + jc);
                float x[6], y[6];
                x[0] = lx[jc - 1]; x[1] = xm.x; x[2] = xm.y; x[3] = xm.z; x[4] = xm.w; x[5] = lx[jc + 4];
                y[0] = ly[jc - 1]; y[1] = ym.x; y[2] = ym.y; y[3] = ym.z; y[4] = ym.w; y[5] = ly[jc + 4];
#pragma unroll
                for (int i = 0; i < 6; i++) {
                    vx[i] += x[i];
                    vy[i] += y[i];
                    vss[i] = fmaf(x[i], x[i], fmaf(y[i], y[i], vss[i]));
                    vxy[i] = fmaf(x[i], y[i], vxy[i]);
                }
                if (r3 == 1) {
#pragma unroll
                    for (int k = 0; k < 4; k++) dab[k] = fabsf(x[k + 1] - y[k + 1]);
                }
            }

#pragma unroll
            for (int k = 0; k < 4; k++) {
                float Sx  = vx [k] + vx [k + 1] + vx [k + 2];
                float Sy  = vy [k] + vy [k + 1] + vy [k + 2];
                float Sss = vss[k] + vss[k + 1] + vss[k + 2];
                float Sxy = vxy[k] + vxy[k + 1] + vxy[k + 2];

                float mux = Sx * inv9;
                float muy = Sy * inv9;
                float mm  = mux * muy;
                // sigx + sigy = Sss/9 - mux - muy   (faithful: -mu, not -mu^2)
                float sigsum = fmaf(Sss, inv9, -(mux + muy));
                float sigxy  = fmaf(Sxy, inv9, -mm);

                float num = fmaf(2.0f, mm, C1v) * fmaf(2.0f, sigxy, C2v);
                float den = fmaf(muy, muy, fmaf(mux, mux, C1v)) * (sigsum + C2v);
                float q   = num * __builtin_amdgcn_rcpf(den);
                float ns  = fmaf(q, -0.5f, 0.5f);
                ns = fminf(fmaxf(ns, 0.0f), 1.0f);

                acc[rr][k] = fmaf(wssim, ns, fmaf(wl1, dab[k], acc[rr][k]));
            }
        }
        __syncthreads();   // protect LDS before next channel's staging
    }

#pragma unroll
    for (int rr = 0; rr < 2; rr++) {
        const int oh = h0 + 2 * ty + rr;
        *(float4*)(out + ((size_t)b * HH + oh) * WW + bx * OTW + 4 * tx) =
            make_float4(acc[rr][0], acc[rr][1], acc[rr][2], acc[rr][3]);
    }
}

extern "C" void kernel_launch(void* const* d_in, const int* in_sizes, int n_in,
                              void* d_out, int out_size, void* d_ws, size_t ws_size,
                              hipStream_t stream) {
    const float* src = (const float*)d_in[0];   // 'output'
    const float* tgt = (const float*)d_in[1];   // 'target'
    float* out = (float*)d_out;

    dim3 grid(WW / OTW, HH / OTH, BATCH);       // (5, 24, 32) = 3840 blocks
    dim3 block(32, 8);
    ssim_l1_kernel<<<grid, block, 0, stream>>>(src, tgt, out);
}